// Round 2
// baseline (123.596 us; speedup 1.0000x reference)
//
#include <hip/hip_runtime.h>

typedef unsigned int  u32;
typedef unsigned short u16;

typedef float f4  __attribute__((ext_vector_type(4)));
typedef short bf8 __attribute__((ext_vector_type(8)));

#define NBLK  2048
#define ITERS 2      // 2048 blocks * 2 iters * 64 boards = 262144
#define ZSTR  104    // z1 row stride in u16: 52 dwords == 20 mod 32 -> balanced banks

// round-to-nearest-even fp32 -> bf16 bits
__device__ __forceinline__ u32 bfr(float f) {
    union { float f; u32 u; } v; v.f = f;
    return (v.u + 0x7fffu + ((v.u >> 16) & 1u)) >> 16;
}
__device__ __forceinline__ u32 pk2(float lo, float hi) { return bfr(lo) | (bfr(hi) << 16); }
__device__ __forceinline__ u32 pk16(u32 lo, u32 hi)    { return lo | (hi << 16); }
__device__ __forceinline__ float blo(u32 u) { union { u32 u; float f; } v; v.u = u << 16;        return v.f; }
__device__ __forceinline__ float bhi(u32 u) { union { u32 u; float f; } v; v.u = u & 0xffff0000u; return v.f; }
// reverse 4 nibbles of a 16-bit row
__device__ __forceinline__ u32 nrev(u32 x) {
    return ((x >> 12) & 0xFu) | ((x >> 4) & 0xF0u) | ((x << 4) & 0xF00u) | ((x << 12) & 0xF000u);
}

__launch_bounds__(256, 2)
__global__ void smartcnn_fused(const int* __restrict__ exps,
                               const float* __restrict__ c0w, const float* __restrict__ c0b,
                               const float* __restrict__ c1w,
                               const float* __restrict__ lw,  const float* __restrict__ lb,
                               const float* __restrict__ ow,  const float* __restrict__ ob,
                               float* __restrict__ out)
{
    __shared__ u16    Th[4 * 128];      // Th[c][v1*11+v2] = bf16(relu(conv0 pair sum + bias))
    __shared__ u16    Tv[4 * 128];      // Tv[c][v1*11+v2] = bf16(relu(conv1 pair sum))
    __shared__ u16    z1[64 * ZSTR];    // [G*16+m][k] bf16, padded row
    __shared__ float4 Pbuf[4][4][16];   // [G][wave][m] logit partials
    __shared__ u32    flg[64];          // [G*16+m] flip flags

    const int tid  = threadIdx.x;
    const int w    = tid >> 6;    // wave 0..3: owns feature rows 64w..64w+63
    const int lane = tid & 63;
    const int m    = lane & 15;
    const int qd   = lane >> 4;   // quad 0..3 (= conv channel in phase 1)

    // ---- build 2D pair tables: relu+sum+bf16-round folded in (exact f32 sum, RNE) ----
    for (int i = tid; i < 484; i += 256) {
        int c = i / 121, r = i - c * 121, v1 = r / 11, v2 = r - v1 * 11;
        float hsum = c0w[c*24 + 0] + c0w[c*24 + (1+v1)*2 + 0] + c0b[c]
                   + c0w[c*24 + 1] + c0w[c*24 + (1+v2)*2 + 1];
        float vsum = c1w[c*24 + 0] + c1w[c*24 + (1+v1)*2 + 0]
                   + c1w[c*24 + 1] + c1w[c*24 + (1+v2)*2 + 1];
        Th[c*128 + r] = (u16)bfr(fmaxf(hsum, 0.f));
        Tv[c*128 + r] = (u16)bfr(fmaxf(vsum, 0.f));
    }

    // ---- preload W A-fragments (rows 64w..64w+63, K=96) into registers ----
    bf8 af[4][3];
    #pragma unroll
    for (int tt = 0; tt < 4; ++tt) {
        #pragma unroll
        for (int s = 0; s < 3; ++s) {
            const float* src = lw + ((size_t)((w*4 + tt)*16 + m))*96 + s*32 + qd*8;
            float4 x0 = *(const float4*)(src);
            float4 x1 = *(const float4*)(src + 4);
            union { u32 u[4]; bf8 v; } cv;
            cv.u[0] = pk2(x0.x, x0.y); cv.u[1] = pk2(x0.z, x0.w);
            cv.u[2] = pk2(x1.x, x1.y); cv.u[3] = pk2(x1.z, x1.w);
            af[tt][s] = cv.v;
        }
    }
    // ---- preload out_w (bf16 pairs) + linear_b for this lane's feature rows ----
    u32 owp[4][4][2]; f4 lb4[4];
    #pragma unroll
    for (int tt = 0; tt < 4; ++tt) {
        #pragma unroll
        for (int r = 0; r < 4; ++r) {
            int n = (w*4 + tt)*16 + qd*4 + r;
            owp[tt][r][0] = pk2(ow[0*256 + n], ow[1*256 + n]);
            owp[tt][r][1] = pk2(ow[2*256 + n], ow[3*256 + n]);
            lb4[tt][r] = lb[n];
        }
    }
    const float4 obv = *(const float4*)ob;

    __syncthreads();

    const int boardBase0 = blockIdx.x * (ITERS * 64);
    // prefetch first iteration's exponents: lane (qd,m) loads row qd of board m (group w)
    int4 e4 = *(const int4*)(exps + (size_t)(boardBase0 + w*16 + m)*16 + qd*4);

    for (int it = 0; it < ITERS; ++it) {
        const int base = boardBase0 + it*64;

        // ================= phase 1: build z1 for group G = w =================
        u32 p = (u32)e4.x | ((u32)e4.y << 4) | ((u32)e4.z << 8) | ((u32)e4.w << 12);
        u32 R0 = (u32)__shfl((int)p, m);
        u32 R1 = (u32)__shfl((int)p, m + 16);
        u32 R2 = (u32)__shfl((int)p, m + 32);
        u32 R3 = (u32)__shfl((int)p, m + 48);
        // corners of UNFLIPPED board; argmax first-max-wins
        u32 c0v = R0 & 15u, c1v = (R0 >> 12) & 15u, c2v = R3 & 15u, c3v = (R3 >> 12) & 15u;
        u32 best = c0v; int ix = 0;
        if (c1v > best) { best = c1v; ix = 1; }
        if (c2v > best) { best = c2v; ix = 2; }
        if (c3v > best) { best = c3v; ix = 3; }
        const bool fv = (ix >= 2), fh = ((ix & 1) != 0);
        u32 F[4];
        F[0] = fv ? R3 : R0;
        F[1] = fv ? R2 : R1;
        F[2] = fv ? R1 : R2;
        F[3] = fv ? R0 : R3;
        #pragma unroll
        for (int i = 0; i < 4; ++i) F[i] = fh ? nrev(F[i]) : F[i];

        if (qd == 0) flg[w*16 + m] = (u32)fv | ((u32)fh << 1);

        // nibble extraction
        u32 nb[4][4];
        #pragma unroll
        for (int i = 0; i < 4; ++i)
            #pragma unroll
            for (int j = 0; j < 4; ++j)
                nb[i][j] = (F[i] >> (4*j)) & 15u;

        // 2D table gathers: zh[i,j] j=0..2 ; zv[i,j] i=0..2 (values already bf16+relu)
        const u16* ThQ = &Th[qd * 128];
        const u16* TvQ = &Tv[qd * 128];
        u32 hh[12], vv[12];
        #pragma unroll
        for (int i = 0; i < 4; ++i)
            #pragma unroll
            for (int j = 0; j < 3; ++j)
                hh[i*3 + j] = ThQ[nb[i][j]*11u + nb[i][j+1]];
        #pragma unroll
        for (int i = 0; i < 3; ++i)
            #pragma unroll
            for (int j = 0; j < 4; ++j)
                vv[i*4 + j] = TvQ[nb[i][j]*11u + nb[i+1][j]];

        u16* zrow = &z1[(w*16 + m) * ZSTR];
        { // zh run: features c*12 + (i*3+j); zv run: features 48 + c*12 + (i*4+j)
            uint2* ph = (uint2*)(zrow + qd*12);
            ph[0] = make_uint2(pk16(hh[0], hh[1]),  pk16(hh[2], hh[3]));
            ph[1] = make_uint2(pk16(hh[4], hh[5]),  pk16(hh[6], hh[7]));
            ph[2] = make_uint2(pk16(hh[8], hh[9]),  pk16(hh[10], hh[11]));
            uint2* pv = (uint2*)(zrow + 48 + qd*12);
            pv[0] = make_uint2(pk16(vv[0], vv[1]),  pk16(vv[2], vv[3]));
            pv[1] = make_uint2(pk16(vv[4], vv[5]),  pk16(vv[6], vv[7]));
            pv[2] = make_uint2(pk16(vv[8], vv[9]),  pk16(vv[10], vv[11]));
        }

        // prefetch next iteration's exponents (hide HBM latency behind GEMM)
        if (it + 1 < ITERS)
            e4 = *(const int4*)(exps + (size_t)(boardBase0 + (it+1)*64 + w*16 + m)*16 + qd*4);

        __syncthreads();  // z1 ready (all groups)

        // ================= GEMM1 (MFMA) + GEMM2 (VALU, in-register) =================
        bf8 zb[4][3];
        #pragma unroll
        for (int G = 0; G < 4; ++G)
            #pragma unroll
            for (int s = 0; s < 3; ++s)
                zb[G][s] = *(const bf8*)(&z1[(G*16 + m)*ZSTR + s*32 + qd*8]);

        float P[4][4] = {};  // [G][action] partial logits over this lane's features
        #pragma unroll
        for (int tt = 0; tt < 4; ++tt) {
            f4 binit = lb4[tt];            // linear_b folded into MFMA C
            f4 acc[4] = {binit, binit, binit, binit};
            #pragma unroll
            for (int s = 0; s < 3; ++s) {
                #pragma unroll
                for (int G = 0; G < 4; ++G)
                    acc[G] = __builtin_amdgcn_mfma_f32_16x16x32_bf16(af[tt][s], zb[G][s], acc[G], 0, 0, 0);
            }
            // lane holds D rows = features (w*4+tt)*16 + qd*4 + r, col = board m
            #pragma unroll
            for (int r = 0; r < 4; ++r) {
                float w0f = blo(owp[tt][r][0]), w1f = bhi(owp[tt][r][0]);
                float w2f = blo(owp[tt][r][1]), w3f = bhi(owp[tt][r][1]);
                #pragma unroll
                for (int G = 0; G < 4; ++G) {
                    float z = fmaxf(acc[G][r], 0.f);   // relu(z2), bias already in
                    P[G][0] = fmaf(z, w0f, P[G][0]);
                    P[G][1] = fmaf(z, w1f, P[G][1]);
                    P[G][2] = fmaf(z, w2f, P[G][2]);
                    P[G][3] = fmaf(z, w3f, P[G][3]);
                }
            }
        }

        // reduce across quads (features within this wave), then stage for cross-wave sum
        #pragma unroll
        for (int G = 0; G < 4; ++G) {
            #pragma unroll
            for (int a = 0; a < 4; ++a) {
                P[G][a] += __shfl_xor(P[G][a], 16);
                P[G][a] += __shfl_xor(P[G][a], 32);
            }
        }
        if (qd == 0) {
            #pragma unroll
            for (int G = 0; G < 4; ++G)
                Pbuf[G][w][m] = make_float4(P[G][0], P[G][1], P[G][2], P[G][3]);
        }
        __syncthreads();

        // ================= epilogue: lane (qd,m) owns board base + qd*16 + m =================
        {
            float4 s0 = Pbuf[qd][0][m], s1 = Pbuf[qd][1][m], s2 = Pbuf[qd][2][m], s3 = Pbuf[qd][3][m];
            float L0 = s0.x + s1.x + s2.x + s3.x + obv.x;
            float L1 = s0.y + s1.y + s2.y + s3.y + obv.y;
            float L2 = s0.z + s1.z + s2.z + s3.z + obv.z;
            float L3 = s0.w + s1.w + s2.w + s3.w + obv.w;
            float mx = fmaxf(fmaxf(L0, L1), fmaxf(L2, L3));
            float e0 = __expf(L0 - mx), e1 = __expf(L1 - mx), e2 = __expf(L2 - mx), e3 = __expf(L3 - mx);
            float inv = 1.0f / (e0 + e1 + e2 + e3);
            float p0 = e0 * inv, p1 = e1 * inv, p2 = e2 * inv, p3 = e3 * inv;
            u32 fl = flg[qd*16 + m];
            float4 o;
            o.x = (fl & 1u) ? p1 : p0;   // actions 0,1 swap on flip_v
            o.y = (fl & 1u) ? p0 : p1;
            o.z = (fl & 2u) ? p3 : p2;   // actions 2,3 swap on flip_h
            o.w = (fl & 2u) ? p2 : p3;
            *(float4*)(out + (size_t)(base + qd*16 + m) * 4) = o;
        }
        __syncthreads();  // protect z1/flg/Pbuf before next iteration overwrites
    }
}

extern "C" void kernel_launch(void* const* d_in, const int* in_sizes, int n_in,
                              void* d_out, int out_size, void* d_ws, size_t ws_size,
                              hipStream_t stream) {
    const int*   exps = (const int*)  d_in[0];
    const float* c0w  = (const float*)d_in[1];
    const float* c0b  = (const float*)d_in[2];
    const float* c1w  = (const float*)d_in[3];
    const float* lw   = (const float*)d_in[4];
    const float* lbv  = (const float*)d_in[5];
    const float* oww  = (const float*)d_in[6];
    const float* obv  = (const float*)d_in[7];
    smartcnn_fused<<<NBLK, 256, 0, stream>>>(exps, c0w, c0b, c1w, lw, lbv, oww, obv, (float*)d_out);
}